// Round 1
// baseline (137.638 us; speedup 1.0000x reference)
//
#include <hip/hip_runtime.h>
#include <cstddef>

typedef __bf16 bf16_t;
typedef __bf16 bf16x8 __attribute__((ext_vector_type(8)));
typedef float  f32x4  __attribute__((ext_vector_type(4)));

static constexpr int BB = 128;   // batch
static constexpr int NN = 64;    // nodes
static constexpr int FF = 4;     // features
static constexpr int HH = 256;   // hidden

// ---- workspace layout (bytes) ----
// W2p    @ 0       : 8*16*64*8  bf16 = 131072 B   (W_msg2 packed B-frags)
// W1op   @ 131072  : 9*16*64*8  bf16 = 147456 B   (W_out1 padded/remapped)
// W2op   @ 278528  : 8*16*64*8  bf16 = 131072 B   (W_out2 packed)
// innode @ 409600  : 8192*288   bf16 = 4718592 B  ([agg(256) | x(4) | pad(28)])

// ------------------------------------------------------------------
// Pack fp32 weights into MFMA B-fragment order (16x16x32 bf16):
// lane holds B[k = ks*32 + (lane>>4)*8 + j][col = nt*16 + (lane&15)]
// dst[((ks*16+nt)*64 + lane)*8 + j]
// mode 0: src is [K=256][256] row-major, direct.
// mode 1: W_out1 [260][256] remapped to node-input order
//         k<256 -> agg weights (src row 4+k); 256..259 -> x rows 0..3; >=260 -> 0
// ------------------------------------------------------------------
__global__ void pack_w(const float* __restrict__ src, bf16_t* __restrict__ dst,
                       int ksteps, int mode)
{
    int fid = blockIdx.x * 256 + threadIdx.x;
    int total = ksteps * 1024;            // 16 ntiles * 64 lanes
    if (fid >= total) return;
    int lane = fid & 63;
    int nt   = (fid >> 6) & 15;
    int ks   = fid >> 10;
    int col  = nt * 16 + (lane & 15);
    int kb   = ks * 32 + (lane >> 4) * 8;
    #pragma unroll
    for (int j = 0; j < 8; ++j) {
        int k = kb + j;
        float v;
        if (mode == 0) {
            v = src[k * 256 + col];
        } else {
            if (k < 256)      v = src[(4 + k) * 256 + col];
            else if (k < 260) v = src[(k - 256) * 256 + col];
            else              v = 0.f;
        }
        dst[(size_t)fid * 8 + j] = (bf16_t)v;
    }
}

// ------------------------------------------------------------------
// Edge MLP + aggregation. One block = (batch b, receivers i0, i1).
// rows r=0..127: receiver = (r<64 ? i0 : i1), sender j = r&63.
// h1[r] = relu(U_recv + V_j) computed scalar (K=8 layer is trivial),
// stored bf16 in LDS with XOR swizzle; layer 2 is MFMA 16x16x32 bf16
// against globally-prepacked W2p (L2-resident); self-row masked and
// rows summed at the accumulator level -> agg written bf16 to innode.
// ------------------------------------------------------------------
__global__ __launch_bounds__(256, 2) void edge_kernel(
    const float* __restrict__ x,      // [128][64][4]
    const float* __restrict__ W1,     // [8][256]
    const float* __restrict__ b1,     // [256]
    const bf16_t* __restrict__ W2p,   // packed
    const float* __restrict__ b2,     // [256]
    bf16_t* __restrict__ innode)      // [8192][288]
{
    __shared__ __align__(16) char h1[128 * 512];  // 64 KiB bf16, swizzled

    const int tid  = threadIdx.x;
    const int lane = tid & 63;
    const int w    = tid >> 6;
    const int b    = blockIdx.x >> 5;
    const int pr   = blockIdx.x & 31;
    const int i0   = pr * 2, i1 = i0 + 1;

    // per-lane node features: lane <-> node
    float4 xv4 = ((const float4*)x)[b * NN + lane];
    float xc[4] = {xv4.x, xv4.y, xv4.z, xv4.w};

    // ---- h1 phase: thread = (row-group rg 0..7) x (8-col block hb 0..31) ----
    {
        const int hb = tid & 31;
        const int rg = tid >> 5;
        const int h0 = hb * 8;
        float wA[4][8], wB[4][8], U0[8], U1[8];
        #pragma unroll
        for (int f = 0; f < 4; ++f)
            #pragma unroll
            for (int u = 0; u < 8; ++u) {
                wA[f][u] = W1[f * HH + h0 + u];
                wB[f][u] = W1[(4 + f) * HH + h0 + u];
            }
        #pragma unroll
        for (int u = 0; u < 8; ++u) {
            float s0 = b1[h0 + u], s1 = s0;
            #pragma unroll
            for (int f = 0; f < 4; ++f) {
                s0 += x[b * NN * FF + i0 * FF + f] * wA[f][u];
                s1 += x[b * NN * FF + i1 * FF + f] * wA[f][u];
            }
            U0[u] = s0; U1[u] = s1;
        }
        #pragma unroll
        for (int k = 0; k < 16; ++k) {
            int r = rg * 16 + k;          // 0..127
            int j = r & 63;               // sender node
            float xj[4];
            #pragma unroll
            for (int f = 0; f < 4; ++f) xj[f] = __shfl(xc[f], j);
            bf16x8 pk;
            #pragma unroll
            for (int u = 0; u < 8; ++u) {
                float s = (r < 64) ? U0[u] : U1[u];
                #pragma unroll
                for (int f = 0; f < 4; ++f) s += xj[f] * wB[f][u];
                pk[u] = (bf16_t)fmaxf(s, 0.f);
            }
            *(bf16x8*)(h1 + ((r * 512 + hb * 16) ^ ((r & 7) << 4))) = pk;
        }
    }

    // x + zero-pad columns 256..287 of innode (node-MLP input tail)
    if (tid < 64) {
        int node = (tid < 32) ? i0 : i1;
        int c = tid & 31;
        float v = (c < 4) ? x[b * NN * FF + node * FF + c] : 0.f;
        innode[(size_t)(b * NN + node) * 288 + 256 + c] = (bf16_t)v;
    }
    __syncthreads();

    // ---- layer 2: [128,256] @ [256,256], wave owns 8 mtiles x 4 ntiles ----
    const int lm = lane & 15, lk = lane >> 4;
    f32x4 acc[8][4] = {};
    #pragma unroll
    for (int ks = 0; ks < 8; ++ks) {
        bf16x8 a[8];
        #pragma unroll
        for (int mt = 0; mt < 8; ++mt) {
            int r = mt * 16 + lm;
            a[mt] = *(const bf16x8*)(h1 + ((r * 512 + ks * 64 + lk * 16) ^ ((r & 7) << 4)));
        }
        #pragma unroll
        for (int nt = 0; nt < 4; ++nt) {
            bf16x8 bb = *(const bf16x8*)(W2p + (size_t)((ks * 16 + w * 4 + nt) * 64 + lane) * 8);
            #pragma unroll
            for (int mt = 0; mt < 8; ++mt)
                acc[mt][nt] = __builtin_amdgcn_mfma_f32_16x16x32_bf16(a[mt], bb, acc[mt][nt], 0, 0, 0);
        }
    }

    // ---- bias + relu + self-row mask + row-sum (aggregate) ----
    // D layout (m89-verified): col = lane&15, row = (lane>>4)*4 + j
    float b2v[4];
    #pragma unroll
    for (int nt = 0; nt < 4; ++nt) b2v[nt] = b2[w * 64 + nt * 16 + lm];

    float agg0[4] = {0, 0, 0, 0}, agg1[4] = {0, 0, 0, 0};
    #pragma unroll
    for (int mt = 0; mt < 8; ++mt) {
        int rs = (mt < 4) ? i0 : (64 + i1);          // self-row global index
        bool hasSelf = (rs >> 4) == mt;
        int g = (rs & 15) >> 2, js = rs & 3;
        #pragma unroll
        for (int nt = 0; nt < 4; ++nt) {
            float s = 0.f;
            #pragma unroll
            for (int j = 0; j < 4; ++j) {
                float v = fmaxf(acc[mt][nt][j] + b2v[nt], 0.f);
                if (hasSelf && lk == g && j == js) v = 0.f;   // drop self edge
                s += v;
            }
            s += __shfl_xor(s, 16);
            s += __shfl_xor(s, 32);
            if (mt < 4) agg0[nt] += s; else agg1[nt] += s;
        }
    }
    if (lane < 16) {
        #pragma unroll
        for (int nt = 0; nt < 4; ++nt) {
            int col = w * 64 + nt * 16 + lane;
            innode[(size_t)(b * NN + i0) * 288 + col] = (bf16_t)agg0[nt];
            innode[(size_t)(b * NN + i1) * 288 + col] = (bf16_t)agg1[nt];
        }
    }
}

// ------------------------------------------------------------------
// Node MLP: [8192,288] -> relu 256 -> relu 256 -> 4.
// One block = 32 rows; 3 fused layers, MFMA for layers 1-2.
// ------------------------------------------------------------------
__global__ __launch_bounds__(256, 2) void node_kernel(
    const bf16_t* __restrict__ innode,  // [8192][288]
    const bf16_t* __restrict__ W1op,
    const float* __restrict__ bo1,
    const bf16_t* __restrict__ W2op,
    const float* __restrict__ bo2,
    const float* __restrict__ W3,       // [256][4] fp32
    const float* __restrict__ bo3,      // [4]
    float* __restrict__ out)            // [8192][4]
{
    __shared__ __align__(16) char bufA[32 * 640];   // 288 bf16/row, stride padded to 640B (40 chunks, %8==0 for swizzle)
    __shared__ __align__(16) char bufB[32 * 512];   // o1 bf16 swizzled
    __shared__ __align__(16) char bufC[32 * 528];   // o2 bf16, stride 264 elems (bank-spread for layer 3)

    const int tid  = threadIdx.x;
    const int lane = tid & 63;
    const int w    = tid >> 6;
    const int m0   = blockIdx.x * 32;
    const int lm   = lane & 15, lk = lane >> 4;

    for (int idx = tid; idx < 32 * 36; idx += 256) {
        int r = idx / 36, c = idx - r * 36;
        bf16x8 v = *(const bf16x8*)(innode + (size_t)(m0 + r) * 288 + c * 8);
        *(bf16x8*)(bufA + ((r * 640 + c * 16) ^ ((r & 7) << 4))) = v;
    }
    __syncthreads();

    // ---- layer 1: K=288 (9 k-steps) ----
    f32x4 acc[2][4] = {};
    #pragma unroll
    for (int ks = 0; ks < 9; ++ks) {
        bf16x8 a[2];
        #pragma unroll
        for (int mt = 0; mt < 2; ++mt) {
            int r = mt * 16 + lm;
            a[mt] = *(const bf16x8*)(bufA + ((r * 640 + ks * 64 + lk * 16) ^ ((r & 7) << 4)));
        }
        #pragma unroll
        for (int nt = 0; nt < 4; ++nt) {
            bf16x8 bb = *(const bf16x8*)(W1op + (size_t)((ks * 16 + w * 4 + nt) * 64 + lane) * 8);
            #pragma unroll
            for (int mt = 0; mt < 2; ++mt)
                acc[mt][nt] = __builtin_amdgcn_mfma_f32_16x16x32_bf16(a[mt], bb, acc[mt][nt], 0, 0, 0);
        }
    }
    #pragma unroll
    for (int nt = 0; nt < 4; ++nt) {
        int col = (w * 4 + nt) * 16 + lm;
        float bias = bo1[col];
        #pragma unroll
        for (int mt = 0; mt < 2; ++mt)
            #pragma unroll
            for (int j = 0; j < 4; ++j) {
                int row = mt * 16 + lk * 4 + j;
                float v = fmaxf(acc[mt][nt][j] + bias, 0.f);
                *(bf16_t*)(bufB + ((row * 512 + col * 2) ^ ((row & 7) << 4))) = (bf16_t)v;
            }
    }
    __syncthreads();

    // ---- layer 2: K=256 (8 k-steps) ----
    f32x4 acc2[2][4] = {};
    #pragma unroll
    for (int ks = 0; ks < 8; ++ks) {
        bf16x8 a[2];
        #pragma unroll
        for (int mt = 0; mt < 2; ++mt) {
            int r = mt * 16 + lm;
            a[mt] = *(const bf16x8*)(bufB + ((r * 512 + ks * 64 + lk * 16) ^ ((r & 7) << 4)));
        }
        #pragma unroll
        for (int nt = 0; nt < 4; ++nt) {
            bf16x8 bb = *(const bf16x8*)(W2op + (size_t)((ks * 16 + w * 4 + nt) * 64 + lane) * 8);
            #pragma unroll
            for (int mt = 0; mt < 2; ++mt)
                acc2[mt][nt] = __builtin_amdgcn_mfma_f32_16x16x32_bf16(a[mt], bb, acc2[mt][nt], 0, 0, 0);
        }
    }
    bf16_t* c16 = (bf16_t*)bufC;
    #pragma unroll
    for (int nt = 0; nt < 4; ++nt) {
        int col = (w * 4 + nt) * 16 + lm;
        float bias = bo2[col];
        #pragma unroll
        for (int mt = 0; mt < 2; ++mt)
            #pragma unroll
            for (int j = 0; j < 4; ++j) {
                int row = mt * 16 + lk * 4 + j;
                float v = fmaxf(acc2[mt][nt][j] + bias, 0.f);
                c16[row * 264 + col] = (bf16_t)v;
            }
    }
    __syncthreads();

    // ---- layer 3: [32,256] @ [256,4] + bias (no relu) ----
    if (tid < 128) {
        int m = tid >> 2, o = tid & 3;
        float s = bo3[o];
        #pragma unroll 8
        for (int k = 0; k < 256; ++k)
            s += (float)c16[m * 264 + k] * W3[k * 4 + o];
        out[(size_t)(m0 + m) * 4 + o] = s;
    }
}

// ------------------------------------------------------------------
extern "C" void kernel_launch(void* const* d_in, const int* in_sizes, int n_in,
                              void* d_out, int out_size, void* d_ws, size_t ws_size,
                              hipStream_t stream)
{
    (void)in_sizes; (void)n_in; (void)out_size; (void)ws_size;
    const float* x      = (const float*)d_in[0];
    // d_in[1..3] (edges, rel_rec, rel_send) unused: graph structure is fixed
    const float* W_msg1 = (const float*)d_in[4];
    const float* b_msg1 = (const float*)d_in[5];
    const float* W_msg2 = (const float*)d_in[6];
    const float* b_msg2 = (const float*)d_in[7];
    const float* W_out1 = (const float*)d_in[8];
    const float* b_out1 = (const float*)d_in[9];
    const float* W_out2 = (const float*)d_in[10];
    const float* b_out2 = (const float*)d_in[11];
    const float* W_out3 = (const float*)d_in[12];
    const float* b_out3 = (const float*)d_in[13];
    float* out = (float*)d_out;

    char* ws = (char*)d_ws;
    bf16_t* W2p    = (bf16_t*)(ws + 0);
    bf16_t* W1op   = (bf16_t*)(ws + 131072);
    bf16_t* W2op   = (bf16_t*)(ws + 278528);
    bf16_t* innode = (bf16_t*)(ws + 409600);

    pack_w<<<32, 256, 0, stream>>>(W_msg2, W2p, 8, 0);
    pack_w<<<36, 256, 0, stream>>>(W_out1, W1op, 9, 1);
    pack_w<<<32, 256, 0, stream>>>(W_out2, W2op, 8, 0);

    edge_kernel<<<4096, 256, 0, stream>>>(x, W_msg1, b_msg1, W2p, b_msg2, innode);
    node_kernel<<<256, 256, 0, stream>>>(innode, W1op, b_out1, W2op, b_out2,
                                         W_out3, b_out3, out);
}

// Round 2
// 127.026 us; speedup vs baseline: 1.0835x; 1.0835x over previous
//
#include <hip/hip_runtime.h>
#include <cstddef>

typedef __bf16 bf16_t;
typedef __bf16 bf16x8 __attribute__((ext_vector_type(8)));
typedef float  f32x4  __attribute__((ext_vector_type(4)));

static constexpr int BB = 128;   // batch
static constexpr int NN = 64;    // nodes
static constexpr int FF = 4;     // features
static constexpr int HH = 256;   // hidden

// ---- workspace layout (bytes) ----
// W2p    @ 0       : 131072   (W_msg2 packed B-frags, bf16)
// W1op   @ 131072  : 147456   (W_out1 padded/remapped, bf16)
// W2op   @ 278528  : 131072   (W_out2 packed, bf16)
// innode @ 409600  : 4718592  ([agg(256) | x(4) | pad(28)] bf16, 8192 rows)
// Vp     @ 5128192 : 4194304  (V = x @ W1[4:8], bf16 [128][64][256])

// ------------------------------------------------------------------
// Pack fp32 weights into MFMA B-fragment order (16x16x32 bf16):
// lane holds B[k = ks*32 + (lane>>4)*8 + j][col = nt*16 + (lane&15)]
// dst[((ks*16+nt)*64 + lane)*8 + j]
// mode 0: src is [K=256][256] row-major, direct.
// mode 1: W_out1 [260][256] remapped to node-input order
// ------------------------------------------------------------------
__global__ void pack_w(const float* __restrict__ src, bf16_t* __restrict__ dst,
                       int ksteps, int mode)
{
    int fid = blockIdx.x * 256 + threadIdx.x;
    int total = ksteps * 1024;            // 16 ntiles * 64 lanes
    if (fid >= total) return;
    int lane = fid & 63;
    int nt   = (fid >> 6) & 15;
    int ks   = fid >> 10;
    int col  = nt * 16 + (lane & 15);
    int kb   = ks * 32 + (lane >> 4) * 8;
    #pragma unroll
    for (int j = 0; j < 8; ++j) {
        int k = kb + j;
        float v;
        if (mode == 0) {
            v = src[k * 256 + col];
        } else {
            if (k < 256)      v = src[(4 + k) * 256 + col];
            else if (k < 260) v = src[(k - 256) * 256 + col];
            else              v = 0.f;
        }
        dst[(size_t)fid * 8 + j] = (bf16_t)v;
    }
}

// ------------------------------------------------------------------
// V[b][n][h] = sum_f x[b][n][f] * W1[(4+f)][h]  (sender-side half of layer 1)
// Computed once per (batch,node) instead of once per receiver-pair block.
// ------------------------------------------------------------------
__global__ void prep_v(const float* __restrict__ x, const float* __restrict__ W1,
                       bf16_t* __restrict__ Vp)
{
    int gid  = blockIdx.x * 256 + threadIdx.x;   // 262144 total
    int rown = gid >> 5;                          // 0..8191 = b*64+n
    int hb   = gid & 31;
    int h0   = hb * 8;
    float4 xv = ((const float4*)x)[rown];
    bf16x8 o;
    #pragma unroll
    for (int u = 0; u < 8; ++u) {
        float s = xv.x * W1[4 * HH + h0 + u] + xv.y * W1[5 * HH + h0 + u]
                + xv.z * W1[6 * HH + h0 + u] + xv.w * W1[7 * HH + h0 + u];
        o[u] = (bf16_t)s;
    }
    *(bf16x8*)(Vp + (size_t)rown * HH + h0) = o;
}

// ------------------------------------------------------------------
// Edge MLP + aggregation. One block = (batch b, receivers i0, i1).
// rows r=0..127: receiver = (r<64 ? i0 : i1), sender j = r&63.
// h1[r] = relu(U_recv + V_j); U computed in-kernel (2 rows), V preloaded.
// Self rows stored as 0; correction: agg -= relu(b2) (since zero-row
// yields relu(bias) through layer 2). Bias folded into MFMA C-init.
// 512 threads = 8 waves: wave = (mt-half: w>>2) x (nt-quad: w&3).
// ------------------------------------------------------------------
__global__ __launch_bounds__(512, 4) void edge_kernel(
    const float* __restrict__ x,      // [128][64][4]
    const float* __restrict__ W1,     // [8][256]
    const float* __restrict__ b1,     // [256]
    const bf16_t* __restrict__ Vp,    // [128][64][256]
    const bf16_t* __restrict__ W2p,   // packed
    const float* __restrict__ b2,     // [256]
    bf16_t* __restrict__ innode)      // [8192][288]
{
    __shared__ __align__(16) char h1[128 * 512];  // 64 KiB bf16, swizzled

    const int tid  = threadIdx.x;
    const int lane = tid & 63;
    const int w    = tid >> 6;
    const int b    = blockIdx.x >> 5;
    const int pr   = blockIdx.x & 31;
    const int i0   = pr * 2, i1 = i0 + 1;

    // ---- h1 phase: thread = (row-group rg 0..15, 8 rows) x (8-col block) ----
    {
        const int hb = tid & 31;
        const int rg = tid >> 5;
        const int h0 = hb * 8;
        const int recv = (rg < 8) ? i0 : i1;

        float xr[4];
        #pragma unroll
        for (int f = 0; f < 4; ++f) xr[f] = x[(b * NN + recv) * FF + f];
        float U[8];
        #pragma unroll
        for (int u = 0; u < 8; ++u) {
            float s = b1[h0 + u];
            #pragma unroll
            for (int f = 0; f < 4; ++f) s += xr[f] * W1[f * HH + h0 + u];
            U[u] = s;
        }
        const int j0 = (rg & 7) * 8;
        #pragma unroll
        for (int k = 0; k < 8; ++k) {
            int r = rg * 8 + k;
            int j = j0 + k;
            bf16x8 v = *(const bf16x8*)(Vp + (size_t)(b * NN + j) * HH + h0);
            bool self = (j == recv);
            bf16x8 pk;
            #pragma unroll
            for (int u = 0; u < 8; ++u) {
                float s = fmaxf(U[u] + (float)v[u], 0.f);
                pk[u] = (bf16_t)(self ? 0.f : s);
            }
            *(bf16x8*)(h1 + ((r * 512 + hb * 16) ^ ((r & 7) << 4))) = pk;
        }
    }

    // x + zero-pad columns 256..287 of innode (node-MLP input tail)
    if (tid < 64) {
        int node = (tid < 32) ? i0 : i1;
        int c = tid & 31;
        float v = (c < 4) ? x[(b * NN + node) * FF + c] : 0.f;
        innode[(size_t)(b * NN + node) * 288 + 256 + c] = (bf16_t)v;
    }
    __syncthreads();

    // ---- layer 2: [128,256] @ [256,256]; wave owns 4 mtiles x 4 ntiles ----
    const int lm = lane & 15, lk = lane >> 4;
    const int mth = w >> 2;          // 0: rows 0..63 (recv i0), 1: rows 64..127 (i1)
    const int ntq = w & 3;           // ntiles ntq*4 .. +3

    float b2v[4];
    #pragma unroll
    for (int nt = 0; nt < 4; ++nt) b2v[nt] = b2[(ntq * 4 + nt) * 16 + lm];

    f32x4 acc[4][4];
    #pragma unroll
    for (int mt = 0; mt < 4; ++mt)
        #pragma unroll
        for (int nt = 0; nt < 4; ++nt)
            acc[mt][nt] = (f32x4){b2v[nt], b2v[nt], b2v[nt], b2v[nt]};

    #pragma unroll
    for (int ks = 0; ks < 8; ++ks) {
        bf16x8 a[4];
        #pragma unroll
        for (int mt = 0; mt < 4; ++mt) {
            int r = (mth * 4 + mt) * 16 + lm;
            a[mt] = *(const bf16x8*)(h1 + ((r * 512 + ks * 64 + lk * 16) ^ ((r & 7) << 4)));
        }
        #pragma unroll
        for (int nt = 0; nt < 4; ++nt) {
            bf16x8 bb = *(const bf16x8*)(W2p + (size_t)((ks * 16 + ntq * 4 + nt) * 64 + lane) * 8);
            #pragma unroll
            for (int mt = 0; mt < 4; ++mt)
                acc[mt][nt] = __builtin_amdgcn_mfma_f32_16x16x32_bf16(a[mt], bb, acc[mt][nt], 0, 0, 0);
        }
    }

    // ---- relu + row-sum (aggregate); self handled by zero-row + relu(b2) sub ----
    const int recv = (mth == 0) ? i0 : i1;
    float agg[4] = {0, 0, 0, 0};
    #pragma unroll
    for (int mt = 0; mt < 4; ++mt)
        #pragma unroll
        for (int nt = 0; nt < 4; ++nt) {
            float s = fmaxf(acc[mt][nt][0], 0.f);
            s += fmaxf(acc[mt][nt][1], 0.f);
            s += fmaxf(acc[mt][nt][2], 0.f);
            s += fmaxf(acc[mt][nt][3], 0.f);
            agg[nt] += s;
        }
    #pragma unroll
    for (int nt = 0; nt < 4; ++nt) {
        agg[nt] += __shfl_xor(agg[nt], 16);
        agg[nt] += __shfl_xor(agg[nt], 32);
    }
    if (lane < 16) {
        #pragma unroll
        for (int nt = 0; nt < 4; ++nt) {
            int col = (ntq * 4 + nt) * 16 + lane;
            innode[(size_t)(b * NN + recv) * 288 + col] =
                (bf16_t)(agg[nt] - fmaxf(b2v[nt], 0.f));
        }
    }
}

// ------------------------------------------------------------------
// Node MLP: [8192,288] -> relu 256 -> relu 256 -> 4.
// One block = 32 rows; 3 fused layers, MFMA for layers 1-2.
// ------------------------------------------------------------------
__global__ __launch_bounds__(256, 2) void node_kernel(
    const bf16_t* __restrict__ innode,  // [8192][288]
    const bf16_t* __restrict__ W1op,
    const float* __restrict__ bo1,
    const bf16_t* __restrict__ W2op,
    const float* __restrict__ bo2,
    const float* __restrict__ W3,       // [256][4] fp32
    const float* __restrict__ bo3,      // [4]
    float* __restrict__ out)            // [8192][4]
{
    __shared__ __align__(16) char bufA[32 * 640];
    __shared__ __align__(16) char bufB[32 * 512];
    __shared__ __align__(16) char bufC[32 * 528];

    const int tid  = threadIdx.x;
    const int lane = tid & 63;
    const int w    = tid >> 6;
    const int m0   = blockIdx.x * 32;
    const int lm   = lane & 15, lk = lane >> 4;

    for (int idx = tid; idx < 32 * 36; idx += 256) {
        int r = idx / 36, c = idx - r * 36;
        bf16x8 v = *(const bf16x8*)(innode + (size_t)(m0 + r) * 288 + c * 8);
        *(bf16x8*)(bufA + ((r * 640 + c * 16) ^ ((r & 7) << 4))) = v;
    }
    __syncthreads();

    // ---- layer 1: K=288 (9 k-steps) ----
    f32x4 acc[2][4] = {};
    #pragma unroll
    for (int ks = 0; ks < 9; ++ks) {
        bf16x8 a[2];
        #pragma unroll
        for (int mt = 0; mt < 2; ++mt) {
            int r = mt * 16 + lm;
            a[mt] = *(const bf16x8*)(bufA + ((r * 640 + ks * 64 + lk * 16) ^ ((r & 7) << 4)));
        }
        #pragma unroll
        for (int nt = 0; nt < 4; ++nt) {
            bf16x8 bb = *(const bf16x8*)(W1op + (size_t)((ks * 16 + w * 4 + nt) * 64 + lane) * 8);
            #pragma unroll
            for (int mt = 0; mt < 2; ++mt)
                acc[mt][nt] = __builtin_amdgcn_mfma_f32_16x16x32_bf16(a[mt], bb, acc[mt][nt], 0, 0, 0);
        }
    }
    #pragma unroll
    for (int nt = 0; nt < 4; ++nt) {
        int col = (w * 4 + nt) * 16 + lm;
        float bias = bo1[col];
        #pragma unroll
        for (int mt = 0; mt < 2; ++mt)
            #pragma unroll
            for (int j = 0; j < 4; ++j) {
                int row = mt * 16 + lk * 4 + j;
                float v = fmaxf(acc[mt][nt][j] + bias, 0.f);
                *(bf16_t*)(bufB + ((row * 512 + col * 2) ^ ((row & 7) << 4))) = (bf16_t)v;
            }
    }
    __syncthreads();

    // ---- layer 2: K=256 (8 k-steps) ----
    f32x4 acc2[2][4] = {};
    #pragma unroll
    for (int ks = 0; ks < 8; ++ks) {
        bf16x8 a[2];
        #pragma unroll
        for (int mt = 0; mt < 2; ++mt) {
            int r = mt * 16 + lm;
            a[mt] = *(const bf16x8*)(bufB + ((r * 512 + ks * 64 + lk * 16) ^ ((r & 7) << 4)));
        }
        #pragma unroll
        for (int nt = 0; nt < 4; ++nt) {
            bf16x8 bb = *(const bf16x8*)(W2op + (size_t)((ks * 16 + w * 4 + nt) * 64 + lane) * 8);
            #pragma unroll
            for (int mt = 0; mt < 2; ++mt)
                acc2[mt][nt] = __builtin_amdgcn_mfma_f32_16x16x32_bf16(a[mt], bb, acc2[mt][nt], 0, 0, 0);
        }
    }
    bf16_t* c16 = (bf16_t*)bufC;
    #pragma unroll
    for (int nt = 0; nt < 4; ++nt) {
        int col = (w * 4 + nt) * 16 + lm;
        float bias = bo2[col];
        #pragma unroll
        for (int mt = 0; mt < 2; ++mt)
            #pragma unroll
            for (int j = 0; j < 4; ++j) {
                int row = mt * 16 + lk * 4 + j;
                float v = fmaxf(acc2[mt][nt][j] + bias, 0.f);
                c16[row * 264 + col] = (bf16_t)v;
            }
    }
    __syncthreads();

    // ---- layer 3: [32,256] @ [256,4] + bias (no relu) ----
    if (tid < 128) {
        int m = tid >> 2, o = tid & 3;
        float s = bo3[o];
        #pragma unroll 8
        for (int k = 0; k < 256; ++k)
            s += (float)c16[m * 264 + k] * W3[k * 4 + o];
        out[(size_t)(m0 + m) * 4 + o] = s;
    }
}

// ------------------------------------------------------------------
extern "C" void kernel_launch(void* const* d_in, const int* in_sizes, int n_in,
                              void* d_out, int out_size, void* d_ws, size_t ws_size,
                              hipStream_t stream)
{
    (void)in_sizes; (void)n_in; (void)out_size; (void)ws_size;
    const float* x      = (const float*)d_in[0];
    const float* W_msg1 = (const float*)d_in[4];
    const float* b_msg1 = (const float*)d_in[5];
    const float* W_msg2 = (const float*)d_in[6];
    const float* b_msg2 = (const float*)d_in[7];
    const float* W_out1 = (const float*)d_in[8];
    const float* b_out1 = (const float*)d_in[9];
    const float* W_out2 = (const float*)d_in[10];
    const float* b_out2 = (const float*)d_in[11];
    const float* W_out3 = (const float*)d_in[12];
    const float* b_out3 = (const float*)d_in[13];
    float* out = (float*)d_out;

    char* ws = (char*)d_ws;
    bf16_t* W2p    = (bf16_t*)(ws + 0);
    bf16_t* W1op   = (bf16_t*)(ws + 131072);
    bf16_t* W2op   = (bf16_t*)(ws + 278528);
    bf16_t* innode = (bf16_t*)(ws + 409600);
    bf16_t* Vp     = (bf16_t*)(ws + 5128192);

    pack_w<<<32, 256, 0, stream>>>(W_msg2, W2p, 8, 0);
    pack_w<<<36, 256, 0, stream>>>(W_out1, W1op, 9, 1);
    pack_w<<<32, 256, 0, stream>>>(W_out2, W2op, 8, 0);
    prep_v<<<1024, 256, 0, stream>>>(x, W_msg1, Vp);

    edge_kernel<<<4096, 512, 0, stream>>>(x, W_msg1, b_msg1, Vp, W2p, b_msg2, innode);
    node_kernel<<<256, 256, 0, stream>>>(innode, W1op, b_out1, W2op, b_out2,
                                         W_out3, b_out3, out);
}

// Round 3
// 96.973 us; speedup vs baseline: 1.4193x; 1.3099x over previous
//
#include <hip/hip_runtime.h>
#include <cstddef>

typedef _Float16 f16_t;
typedef _Float16 f16x8 __attribute__((ext_vector_type(8)));
typedef float    f32x4 __attribute__((ext_vector_type(4)));

static constexpr int NN = 64;    // nodes
static constexpr int FF = 4;     // features
static constexpr int HH = 256;   // hidden

// ---- workspace layout (bytes) ----
// W2p    @ 0       : 131072   (W_msg2 packed B-frags, f16)
// W1op   @ 131072  : 147456   (W_out1 padded/remapped, f16)
// W2op   @ 278528  : 131072   (W_out2 packed, f16)
// innode @ 409600  : 4718592  ([agg(256) | x(4) | pad(28)] f16, 8192 rows)
// Vp     @ 5128192 : 4194304  (V = x @ W1[4:8], f16 [128][64][256])

// ------------------------------------------------------------------
// B-fragment pack (16x16x32): lane holds B[k=ks*32+(lane>>4)*8+j][col=nt*16+(lane&15)]
// ------------------------------------------------------------------
__device__ inline void pack_frag(const float* __restrict__ src, f16_t* __restrict__ dst,
                                 int fid, int ksteps, int mode)
{
    if (fid >= ksteps * 1024) return;
    int lane = fid & 63;
    int nt   = (fid >> 6) & 15;
    int ks   = fid >> 10;
    int col  = nt * 16 + (lane & 15);
    int kb   = ks * 32 + (lane >> 4) * 8;
    #pragma unroll
    for (int j = 0; j < 8; ++j) {
        int k = kb + j;
        float v;
        if (mode == 0) {
            v = src[k * 256 + col];
        } else {
            if (k < 256)      v = src[(4 + k) * 256 + col];
            else if (k < 260) v = src[(k - 256) * 256 + col];
            else              v = 0.f;
        }
        dst[(size_t)fid * 8 + j] = (f16_t)v;
    }
}

// ------------------------------------------------------------------
// Fused prep: 3 weight packs + V precompute in one launch.
// blocks [0,32): W2p  [32,68): W1op  [68,100): W2op  [100,1124): Vp
// ------------------------------------------------------------------
__global__ void prep_all(const float* __restrict__ x,
                         const float* __restrict__ W_msg1,
                         const float* __restrict__ W_msg2,
                         const float* __restrict__ W_out1,
                         const float* __restrict__ W_out2,
                         f16_t* __restrict__ W2p, f16_t* __restrict__ W1op,
                         f16_t* __restrict__ W2op, f16_t* __restrict__ Vp)
{
    int bid = blockIdx.x, tid = threadIdx.x;
    if (bid < 32) {
        pack_frag(W_msg2, W2p, bid * 256 + tid, 8, 0);
    } else if (bid < 68) {
        pack_frag(W_out1, W1op, (bid - 32) * 256 + tid, 9, 1);
    } else if (bid < 100) {
        pack_frag(W_out2, W2op, (bid - 68) * 256 + tid, 8, 0);
    } else {
        int gid  = (bid - 100) * 256 + tid;   // 262144
        int rown = gid >> 5;                   // b*64+n
        int h0   = (gid & 31) * 8;
        float4 xv = ((const float4*)x)[rown];
        f16x8 o;
        #pragma unroll
        for (int u = 0; u < 8; ++u) {
            float s = xv.x * W_msg1[4 * HH + h0 + u] + xv.y * W_msg1[5 * HH + h0 + u]
                    + xv.z * W_msg1[6 * HH + h0 + u] + xv.w * W_msg1[7 * HH + h0 + u];
            o[u] = (f16_t)s;
        }
        *(f16x8*)(Vp + (size_t)rown * HH + h0) = o;
    }
}

// ------------------------------------------------------------------
// Edge MLP + aggregation. One block = (batch b, receivers i0,i1).
// h1[r] = relu(U_recv + V_j) in PACKED fp16 (pk_add + pk_max, no cvts);
// U table (2x256) built once in LDS. Self rows zeroed; corrected by
// subtracting relu(b2) from agg. Bias folded into MFMA C-init.
// ------------------------------------------------------------------
__global__ __launch_bounds__(512, 4) void edge_kernel(
    const float* __restrict__ x,      // [128][64][4]
    const float* __restrict__ W1,     // [8][256]
    const float* __restrict__ b1,     // [256]
    const f16_t* __restrict__ Vp,     // [128][64][256]
    const f16_t* __restrict__ W2p,    // packed
    const float* __restrict__ b2,     // [256]
    f16_t* __restrict__ innode)       // [8192][288]
{
    __shared__ __align__(16) char h1[128 * 512];   // 64 KiB f16, swizzled
    __shared__ __align__(16) f16_t Utab[2][256];

    const int tid  = threadIdx.x;
    const int lane = tid & 63;
    const int w    = tid >> 6;
    const int b    = blockIdx.x >> 5;
    const int pr   = blockIdx.x & 31;
    const int i0   = pr * 2, i1 = i0 + 1;

    // ---- U table: one (recv, h) element per thread ----
    {
        int rs   = tid >> 8;              // 0 -> i0, 1 -> i1
        int h    = tid & 255;
        int node = rs ? i1 : i0;
        const float* xr = x + (b * NN + node) * FF;
        float s = b1[h] + xr[0] * W1[h] + xr[1] * W1[HH + h]
                        + xr[2] * W1[2 * HH + h] + xr[3] * W1[3 * HH + h];
        Utab[rs][h] = (f16_t)s;
    }
    // x + zero-pad tail columns 256..287 of innode
    if (tid < 64) {
        int node = (tid < 32) ? i0 : i1;
        int c = tid & 31;
        float v = (c < 4) ? x[(b * NN + node) * FF + c] : 0.f;
        innode[(size_t)(b * NN + node) * 288 + 256 + c] = (f16_t)v;
    }
    __syncthreads();

    // ---- h1: thread = (row-group rg, 8 rows) x (8-col block hb) ----
    {
        const int hb = tid & 31;
        const int rg = tid >> 5;
        const int h0 = hb * 8;
        const int recv = (rg < 8) ? i0 : i1;
        const f16x8 fz = {};
        f16x8 u8 = *(const f16x8*)&Utab[rg >> 3][h0];
        const int j0 = (rg & 7) * 8;
        const f16x8* vrow = (const f16x8*)(Vp + (size_t)(b * NN + j0) * HH + h0);
        #pragma unroll
        for (int k = 0; k < 8; ++k) {
            int r = rg * 8 + k;
            int j = j0 + k;
            f16x8 v8 = vrow[k * (HH / 8)];
            f16x8 hv = __builtin_elementwise_max(u8 + v8, fz);  // pk_add + pk_max
            if (j == recv) hv = fz;                             // self edge
            *(f16x8*)(h1 + ((r * 512 + hb * 16) ^ ((r & 7) << 4))) = hv;
        }
    }
    __syncthreads();

    // ---- layer 2: [128,256] @ [256,256]; wave = 4 mtiles x 4 ntiles ----
    const int lm = lane & 15, lk = lane >> 4;
    const int mth = w >> 2;           // row half (recv)
    const int ntq = w & 3;            // ntile quad

    float b2v[4];
    #pragma unroll
    for (int nt = 0; nt < 4; ++nt) b2v[nt] = b2[(ntq * 4 + nt) * 16 + lm];

    f32x4 acc[4][4];
    #pragma unroll
    for (int mt = 0; mt < 4; ++mt)
        #pragma unroll
        for (int nt = 0; nt < 4; ++nt)
            acc[mt][nt] = (f32x4){b2v[nt], b2v[nt], b2v[nt], b2v[nt]};

    #pragma unroll
    for (int ks = 0; ks < 8; ++ks) {
        f16x8 a[4];
        #pragma unroll
        for (int mt = 0; mt < 4; ++mt) {
            int r = (mth * 4 + mt) * 16 + lm;
            a[mt] = *(const f16x8*)(h1 + ((r * 512 + ks * 64 + lk * 16) ^ ((r & 7) << 4)));
        }
        #pragma unroll
        for (int nt = 0; nt < 4; ++nt) {
            f16x8 bb = *(const f16x8*)(W2p + (size_t)((ks * 16 + ntq * 4 + nt) * 64 + lane) * 8);
            #pragma unroll
            for (int mt = 0; mt < 4; ++mt)
                acc[mt][nt] = __builtin_amdgcn_mfma_f32_16x16x32_f16(a[mt], bb, acc[mt][nt], 0, 0, 0);
        }
    }

    // ---- relu + row-sum; self handled by zero-row + relu(b2) subtraction ----
    const int recv = (mth == 0) ? i0 : i1;
    float agg[4] = {0, 0, 0, 0};
    #pragma unroll
    for (int mt = 0; mt < 4; ++mt)
        #pragma unroll
        for (int nt = 0; nt < 4; ++nt) {
            float s = fmaxf(acc[mt][nt][0], 0.f);
            s += fmaxf(acc[mt][nt][1], 0.f);
            s += fmaxf(acc[mt][nt][2], 0.f);
            s += fmaxf(acc[mt][nt][3], 0.f);
            agg[nt] += s;
        }
    #pragma unroll
    for (int nt = 0; nt < 4; ++nt) {
        agg[nt] += __shfl_xor(agg[nt], 16);
        agg[nt] += __shfl_xor(agg[nt], 32);
    }
    if (lane < 16) {
        #pragma unroll
        for (int nt = 0; nt < 4; ++nt) {
            int col = (ntq * 4 + nt) * 16 + lane;
            innode[(size_t)(b * NN + recv) * 288 + col] =
                (f16_t)(agg[nt] - fmaxf(b2v[nt], 0.f));
        }
    }
}

// ------------------------------------------------------------------
// Node MLP: [8192,288] -> relu 256 -> relu 256 -> 4.
// 512 threads: wave = (mt = w>>2) x (ntq = w&3); layer 3 uses all lanes
// with a 4-way k-split + shfl reduce.
// ------------------------------------------------------------------
__global__ __launch_bounds__(512, 2) void node_kernel(
    const f16_t* __restrict__ innode,  // [8192][288]
    const f16_t* __restrict__ W1op,
    const float* __restrict__ bo1,
    const f16_t* __restrict__ W2op,
    const float* __restrict__ bo2,
    const float* __restrict__ W3,      // [256][4] fp32
    const float* __restrict__ bo3,     // [4]
    float* __restrict__ out)           // [8192][4]
{
    __shared__ __align__(16) char bufA[32 * 640];
    __shared__ __align__(16) char bufB[32 * 512];
    __shared__ __align__(16) char bufC[32 * 528];

    const int tid  = threadIdx.x;
    const int lane = tid & 63;
    const int w    = tid >> 6;
    const int m0   = blockIdx.x * 32;
    const int lm   = lane & 15, lk = lane >> 4;
    const int mt   = w >> 2;           // 0..1 (16-row half)
    const int ntq  = w & 3;            // 0..3 (4 ntiles)

    for (int idx = tid; idx < 32 * 36; idx += 512) {
        int r = idx / 36, c = idx - r * 36;
        f16x8 v = *(const f16x8*)(innode + (size_t)(m0 + r) * 288 + c * 8);
        *(f16x8*)(bufA + ((r * 640 + c * 16) ^ ((r & 7) << 4))) = v;
    }
    __syncthreads();

    // ---- layer 1: K=288 (9 k-steps), bias in C-init ----
    f32x4 acc1[4];
    #pragma unroll
    for (int nt = 0; nt < 4; ++nt) {
        float bias = bo1[(ntq * 4 + nt) * 16 + lm];
        acc1[nt] = (f32x4){bias, bias, bias, bias};
    }
    #pragma unroll
    for (int ks = 0; ks < 9; ++ks) {
        int r = mt * 16 + lm;
        f16x8 a = *(const f16x8*)(bufA + ((r * 640 + ks * 64 + lk * 16) ^ ((r & 7) << 4)));
        #pragma unroll
        for (int nt = 0; nt < 4; ++nt) {
            f16x8 bb = *(const f16x8*)(W1op + (size_t)((ks * 16 + ntq * 4 + nt) * 64 + lane) * 8);
            acc1[nt] = __builtin_amdgcn_mfma_f32_16x16x32_f16(a, bb, acc1[nt], 0, 0, 0);
        }
    }
    #pragma unroll
    for (int nt = 0; nt < 4; ++nt) {
        int col = (ntq * 4 + nt) * 16 + lm;
        #pragma unroll
        for (int j = 0; j < 4; ++j) {
            int row = mt * 16 + lk * 4 + j;
            float v = fmaxf(acc1[nt][j], 0.f);
            *(f16_t*)(bufB + ((row * 512 + col * 2) ^ ((row & 7) << 4))) = (f16_t)v;
        }
    }
    __syncthreads();

    // ---- layer 2: K=256 (8 k-steps) ----
    f32x4 acc2[4];
    #pragma unroll
    for (int nt = 0; nt < 4; ++nt) {
        float bias = bo2[(ntq * 4 + nt) * 16 + lm];
        acc2[nt] = (f32x4){bias, bias, bias, bias};
    }
    #pragma unroll
    for (int ks = 0; ks < 8; ++ks) {
        int r = mt * 16 + lm;
        f16x8 a = *(const f16x8*)(bufB + ((r * 512 + ks * 64 + lk * 16) ^ ((r & 7) << 4)));
        #pragma unroll
        for (int nt = 0; nt < 4; ++nt) {
            f16x8 bb = *(const f16x8*)(W2op + (size_t)((ks * 16 + ntq * 4 + nt) * 64 + lane) * 8);
            acc2[nt] = __builtin_amdgcn_mfma_f32_16x16x32_f16(a, bb, acc2[nt], 0, 0, 0);
        }
    }
    f16_t* c16 = (f16_t*)bufC;
    #pragma unroll
    for (int nt = 0; nt < 4; ++nt) {
        int col = (ntq * 4 + nt) * 16 + lm;
        #pragma unroll
        for (int j = 0; j < 4; ++j) {
            int row = mt * 16 + lk * 4 + j;
            float v = fmaxf(acc2[nt][j], 0.f);
            c16[row * 264 + col] = (f16_t)v;
        }
    }
    __syncthreads();

    // ---- layer 3: [32,256] @ [256,4]; all 512 threads, 4-way k-split ----
    {
        int m = tid >> 4;          // 0..31
        int o = (tid >> 2) & 3;    // 0..3
        int q = tid & 3;           // k quarter
        const f16_t* crow = c16 + m * 264 + q * 64;
        float s = 0.f;
        int rot = (lane & 15) * 4; // rotate k to spread LDS banks
        #pragma unroll 8
        for (int k = 0; k < 64; ++k) {
            int kk = (k + rot) & 63;
            s += (float)crow[kk] * W3[(q * 64 + kk) * 4 + o];
        }
        s += __shfl_xor(s, 1);
        s += __shfl_xor(s, 2);
        if (q == 0) out[(size_t)(m0 + m) * 4 + o] = s + bo3[o];
    }
}

// ------------------------------------------------------------------
extern "C" void kernel_launch(void* const* d_in, const int* in_sizes, int n_in,
                              void* d_out, int out_size, void* d_ws, size_t ws_size,
                              hipStream_t stream)
{
    (void)in_sizes; (void)n_in; (void)out_size; (void)ws_size;
    const float* x      = (const float*)d_in[0];
    const float* W_msg1 = (const float*)d_in[4];
    const float* b_msg1 = (const float*)d_in[5];
    const float* W_msg2 = (const float*)d_in[6];
    const float* b_msg2 = (const float*)d_in[7];
    const float* W_out1 = (const float*)d_in[8];
    const float* b_out1 = (const float*)d_in[9];
    const float* W_out2 = (const float*)d_in[10];
    const float* b_out2 = (const float*)d_in[11];
    const float* W_out3 = (const float*)d_in[12];
    const float* b_out3 = (const float*)d_in[13];
    float* out = (float*)d_out;

    char* ws = (char*)d_ws;
    f16_t* W2p    = (f16_t*)(ws + 0);
    f16_t* W1op   = (f16_t*)(ws + 131072);
    f16_t* W2op   = (f16_t*)(ws + 278528);
    f16_t* innode = (f16_t*)(ws + 409600);
    f16_t* Vp     = (f16_t*)(ws + 5128192);

    prep_all<<<1124, 256, 0, stream>>>(x, W_msg1, W_msg2, W_out1, W_out2,
                                       W2p, W1op, W2op, Vp);
    edge_kernel<<<4096, 512, 0, stream>>>(x, W_msg1, b_msg1, Vp, W2p, b_msg2, innode);
    node_kernel<<<256, 512, 0, stream>>>(innode, W1op, b_out1, W2op, b_out2,
                                         W_out3, b_out3, out);
}